// Round 21
// baseline (145.245 us; speedup 1.0000x reference)
//
#include <hip/hip_runtime.h>
#include <hip/hip_bf16.h>

typedef unsigned short u16;
typedef unsigned int u32;
typedef __attribute__((ext_vector_type(4))) unsigned short u16x4;
typedef __attribute__((ext_vector_type(8))) unsigned short u16x8;
typedef __attribute__((ext_vector_type(8))) __bf16 bf16x8;
typedef __attribute__((ext_vector_type(4))) float f32x4;

__device__ __forceinline__ u16 f2bf(float f){
  unsigned u = __builtin_bit_cast(unsigned, f);
  u += 0x7FFFu + ((u >> 16) & 1u);
  return (u16)(u >> 16);
}

__device__ __forceinline__ u32 cvtpk(float lo, float hi){
  u32 r;
  asm("v_cvt_pk_bf16_f32 %0, %1, %2" : "=v"(r) : "v"(lo), "v"(hi));
  return r;
}

__device__ __forceinline__ void load_lds16(const void* g, void* l){
  __builtin_amdgcn_global_load_lds((const __attribute__((address_space(1))) unsigned*)g,
                                   (__attribute__((address_space(3))) unsigned*)l, 16, 0, 0);
}

__device__ __forceinline__ void storeC(float* p, float v){ *p = v; }
__device__ __forceinline__ void storeC(u16* p, float v){ *p = f2bf(v); }

// ---------------- fused prep: LN(x|xa)->bf16 (bid<8192) + 4 weight transposes ----
// Wq additionally scaled by log2(e): scores live in the exp2 domain (no-max softmax).
__global__ __launch_bounds__(256) void prep(const float* __restrict__ x, const float* __restrict__ xa,
                                            const float* __restrict__ w, const float* __restrict__ bb,
                                            const float* __restrict__ Wq, const float* __restrict__ Wkv,
                                            const float* __restrict__ Wout,
                                            u16* __restrict__ xn, u16* __restrict__ xan,
                                            u16* __restrict__ WqT, u16* __restrict__ WkT,
                                            u16* __restrict__ WvT, u16* __restrict__ WoT){
  __shared__ float tile[64][65];
  int bid = blockIdx.x, t = threadIdx.x;
  if (bid < 8192){
    int row = bid;
    const float* src; u16* dst;
    if (row < 4096){ src = x + (size_t)row * 1024; dst = xn + (size_t)row * 1024; }
    else { src = xa + (size_t)(row - 4096) * 1024; dst = xan + (size_t)(row - 4096) * 1024; }
    float4 v = ((const float4*)src)[t];
    float s = v.x + v.y + v.z + v.w;
    float ss = v.x*v.x + v.y*v.y + v.z*v.z + v.w*v.w;
#pragma unroll
    for (int o = 32; o > 0; o >>= 1){ s += __shfl_down(s, o); ss += __shfl_down(ss, o); }
    float* red = &tile[0][0];
    int wv = t >> 6;
    if ((t & 63) == 0){ red[wv] = s; red[wv + 4] = ss; }
    __syncthreads();
    if (t == 0){
      red[0] = red[0] + red[1] + red[2] + red[3];
      red[4] = red[4] + red[5] + red[6] + red[7];
    }
    __syncthreads();
    float mu = red[0] * (1.0f/1024.0f);
    float var = red[4] * (1.0f/1024.0f) - mu*mu;
    float rstd = rsqrtf(var + 1e-5f);
    float4 wv4 = ((const float4*)w)[t];
    float4 bv4 = ((const float4*)bb)[t];
    u16x4 o4;
    o4.x = f2bf((v.x - mu) * rstd * wv4.x + bv4.x);
    o4.y = f2bf((v.y - mu) * rstd * wv4.y + bv4.y);
    o4.z = f2bf((v.z - mu) * rstd * wv4.z + bv4.z);
    o4.w = f2bf((v.w - mu) * rstd * wv4.w + bv4.w);
    ((u16x4*)dst)[t] = o4;
    return;
  }
  int tt = bid - 8192;
  int z = tt >> 8, rem = tt & 255;
  int bx = rem & 15, by = rem >> 4;
  const float* in; u16* out; int ldin;
  switch (z){
    case 0:  in = Wq;         out = WqT; ldin = 1024; break;
    case 1:  in = Wkv;        out = WkT; ldin = 2048; break;
    case 2:  in = Wkv + 1024; out = WvT; ldin = 2048; break;
    default: in = Wout;       out = WoT; ldin = 1024; break;
  }
  float scl = (z == 0) ? 1.44269504f : 1.0f;
  int tr = by * 64, tc = bx * 64;
  int r0 = t >> 4, c0 = (t & 15) * 4;
#pragma unroll
  for (int i = 0; i < 4; ++i){
    int r = r0 + i * 16;
    const float4 val = *(const float4*)&in[(size_t)(tr + r) * ldin + tc + c0];
    tile[r][c0] = val.x; tile[r][c0+1] = val.y; tile[r][c0+2] = val.z; tile[r][c0+3] = val.w;
  }
  __syncthreads();
#pragma unroll
  for (int i = 0; i < 4; ++i){
    int n = r0 + i * 16;
    u16x4 o4;
    o4.x = f2bf(tile[c0+0][n] * scl); o4.y = f2bf(tile[c0+1][n] * scl);
    o4.z = f2bf(tile[c0+2][n] * scl); o4.w = f2bf(tile[c0+3][n] * scl);
    *(u16x4*)&out[(size_t)(tc + n) * 1024 + tr + c0] = o4;
  }
}

// ---------------- BMx256 GEMM, BK=64, 8 waves, dbuf, counted vmcnt ----------------
// R17 epilogue: transposed quads pack r=0..3 (consecutive tokens) into one
// u16x4 store -> 4x fewer store instrs, 4x smaller cacheline footprint.
template<int BM, int NQ, int TMASK, typename OutT>
__global__ __launch_bounds__(512, 2) void gemm256(
    const u16* __restrict__ A0, const u16* __restrict__ A1,
    const u16* __restrict__ A2, const u16* __restrict__ A3,
    const u16* __restrict__ B0, const u16* __restrict__ B1,
    const u16* __restrict__ B2, const u16* __restrict__ B3,
    OutT* __restrict__ C0, OutT* __restrict__ C1,
    OutT* __restrict__ C2, OutT* __restrict__ C3){
  constexpr int AI = BM / 64;
  constexpr int FI = BM / 32;
  constexpr int MT = (NQ == 4) ? 16 : 64;
  __shared__ u16 SA[2][BM * 64];
  __shared__ u16 SB[2][16384];
  int tid = threadIdx.x, lane = tid & 63, wave = tid >> 6;
  int g = lane >> 4, r15 = lane & 15;
  int id = blockIdx.x;
  int r8 = id & 7, k = id >> 3;
  int gm = (k >> 2) * 8 + r8;
  int ntile = k & 3;
  int quad = gm / MT;
  int mbase = (gm % MT) * BM, nbase = ntile * 256;
  const u16* A = quad==0?A0:quad==1?A1:quad==2?A2:A3;
  const u16* B = quad==0?B0:quad==1?B1:quad==2?B2:B3;
  OutT* C      = quad==0?C0:quad==1?C1:quad==2?C2:C3;
  int wr = wave >> 2, wc = wave & 3;
  int rsub = lane >> 3;
  int slo  = (lane & 7) ^ ((lane >> 3) & 7);
  int sw8  = (r15 & 7) << 3;
  f32x4 acc[FI][4] = {};

#define STG(kt, b) { \
  int ko = (kt) * 64; \
  _Pragma("unroll") \
  for (int i = 0; i < AI; ++i){ \
    int row = i*64 + wave*8 + rsub; \
    load_lds16(A + (size_t)(mbase + row)*1024 + ko + slo*8, &SA[b][(i*512 + wave*64)*8]); \
  } \
  _Pragma("unroll") \
  for (int i = 0; i < 4; ++i){ \
    int row = i*64 + wave*8 + rsub; \
    load_lds16(B + (size_t)(nbase + row)*1024 + ko + slo*8, &SB[b][(i*512 + wave*64)*8]); \
  } }

  STG(0, 0);
  for (int t = 0; t < 16; ++t){
    int b = t & 1;
    if (t < 15){
      STG(t + 1, b ^ 1);
      if constexpr (AI == 4) asm volatile("s_waitcnt vmcnt(8)" ::: "memory");
      else                   asm volatile("s_waitcnt vmcnt(6)" ::: "memory");
    } else {
      asm volatile("s_waitcnt vmcnt(0)" ::: "memory");
    }
    __builtin_amdgcn_s_barrier();
    __builtin_amdgcn_sched_barrier(0);
    const u16* Al = &SA[b][0];
    const u16* Bl = &SB[b][0];
#pragma unroll
    for (int ks = 0; ks < 2; ++ks){
      bf16x8 af[FI], bfr[4];
#pragma unroll
      for (int fi = 0; fi < FI; ++fi)
        af[fi] = *(const bf16x8*)&Al[(wr*(FI*16) + fi*16 + r15)*64 + ((ks*32 + g*8) ^ sw8)];
#pragma unroll
      for (int fj = 0; fj < 4; ++fj)
        bfr[fj] = *(const bf16x8*)&Bl[(wc*64 + fj*16 + r15)*64 + ((ks*32 + g*8) ^ sw8)];
#pragma unroll
      for (int fi = 0; fi < FI; ++fi)
#pragma unroll
        for (int fj = 0; fj < 4; ++fj)
          acc[fi][fj] = __builtin_amdgcn_mfma_f32_16x16x32_bf16(af[fi], bfr[fj], acc[fi][fj], 0, 0, 0);
    }
    __builtin_amdgcn_s_barrier();
  }
#undef STG

  bool tr = (TMASK >> quad) & 1;
#pragma unroll
  for (int fi = 0; fi < FI; ++fi)
#pragma unroll
    for (int fj = 0; fj < 4; ++fj){
      int colb = nbase + wc*64 + fj*16 + r15;
      int row0 = mbase + wr*(FI*16) + fi*16 + g*4;
      if constexpr (TMASK != 0){
        if (tr){
          // vT[bh][d][token]: r = consecutive tokens -> one packed 8B store
          int bb = row0 >> 10, token = row0 & 1023;   // rows 0..3 same bb (mbase % 256 == 0)
          int hh = colb >> 6, dd = colb & 63;
          u16x4 o;
          o.x = f2bf(acc[fi][fj][0]); o.y = f2bf(acc[fi][fj][1]);
          o.z = f2bf(acc[fi][fj][2]); o.w = f2bf(acc[fi][fj][3]);
          *(u16x4*)((u16*)C + ((size_t)((bb << 4) + hh) * 64 + dd) * 1024 + token) = o;
          continue;
        }
      }
#pragma unroll
      for (int r = 0; r < 4; ++r)
        storeC(&C[(size_t)(row0 + r) * 1024 + colb], acc[fi][fj][r]);
    }
}

// ---------------- flash attention (best-measured variant: ds_write single-buffer,
// register prefetch, in-loop l reduce; 67.4-68.0 us across 4 passing runs) ----
// 1D grid 2048, XCD-bijective decode. 256 thr, 4 waves x 16 q-rows.
// No-max softmax: scores pre-scaled by log2e (Wq), P = exp2(S' - 32).
#define SW(row, col) ((row) * 64 + ((col) ^ (((row) & 7) << 3)))

__device__ __forceinline__ void exchP(const f32x4& s0, const f32x4& s1,
                                      const f32x4& s2, const f32x4& s3,
                                      bool gh, bool g0, bf16x8& pf0, bf16x8& pf1){
  u32 pk00 = cvtpk(s0[0], s0[1]), pk01 = cvtpk(s0[2], s0[3]);
  u32 pk10 = cvtpk(s1[0], s1[1]), pk11 = cvtpk(s1[2], s1[3]);
  u32 pk20 = cvtpk(s2[0], s2[1]), pk21 = cvtpk(s2[2], s2[3]);
  u32 pk30 = cvtpk(s3[0], s3[1]), pk31 = cvtpk(s3[2], s3[3]);
  u32 c0 = gh ? pk10 : pk00, c1 = gh ? pk11 : pk01;
  u32 d0 = gh ? pk00 : pk10, d1 = gh ? pk01 : pk11;
  u32 s1a = __shfl_xor((int)c0, 16), s1b = __shfl_xor((int)c1, 16);
  u32 s2a = __shfl_xor((int)d0, 32), s2b = __shfl_xor((int)d1, 32);
  u32 s3a = __shfl_xor((int)d0, 48), s3b = __shfl_xor((int)d1, 48);
  union UB { u32 w[4]; bf16x8 v; } ub0, ub1;
  ub0.w[0] = gh ? (g0 ? s1a : s2a) : (g0 ? s3a : c0);
  ub0.w[1] = gh ? (g0 ? s1b : s2b) : (g0 ? s3b : c1);
  ub0.w[2] = gh ? (g0 ? c0 : s3a) : (g0 ? s2a : s1a);
  ub0.w[3] = gh ? (g0 ? c1 : s3b) : (g0 ? s2b : s1b);
  u32 e0 = gh ? pk30 : pk20, e1 = gh ? pk31 : pk21;
  u32 f0 = gh ? pk20 : pk30, f1 = gh ? pk21 : pk31;
  u32 t1a = __shfl_xor((int)e0, 16), t1b = __shfl_xor((int)e1, 16);
  u32 t2a = __shfl_xor((int)f0, 32), t2b = __shfl_xor((int)f1, 32);
  u32 t3a = __shfl_xor((int)f0, 48), t3b = __shfl_xor((int)f1, 48);
  ub1.w[0] = gh ? (g0 ? t1a : t2a) : (g0 ? t3a : e0);
  ub1.w[1] = gh ? (g0 ? t1b : t2b) : (g0 ? t3b : e1);
  ub1.w[2] = gh ? (g0 ? e0 : t3a) : (g0 ? t2a : t1a);
  ub1.w[3] = gh ? (g0 ? e1 : t3b) : (g0 ? t2b : t1b);
  pf0 = ub0.v; pf1 = ub1.v;
}

#define MFMA16(a, b, c) __builtin_amdgcn_mfma_f32_16x16x32_bf16(a, b, c, 0, 0, 0)

__global__ __launch_bounds__(256) void flash(const u16* __restrict__ qg, const u16* __restrict__ vTg,
                                             const u16* __restrict__ kag, const u16* __restrict__ vaTg,
                                             u16* __restrict__ xu, u16* __restrict__ xau){
  __shared__ u16 Ks[4096], VTs[4096];
  int tid = threadIdx.x, lane = tid & 63, wave = tid >> 6, g = lane >> 4, r15 = lane & 15;
  int b = blockIdx.x;
  int xcd = b & 7, idx = b >> 3;
  int qt = idx & 15;
  int pair = xcd * 16 + (idx >> 4);
  int bh = pair & 63, dir = pair >> 6;
  size_t tokbase = ((size_t)(bh >> 4)) * 1048576 + (size_t)(bh & 15) * 64;
  size_t vtbase  = (size_t)bh << 16;
  const u16 *Q, *K, *VT; u16* O;
  if (dir == 0){ Q = qg + tokbase;  K = kag + tokbase; VT = vaTg + vtbase; O = xu  + tokbase; }
  else         { Q = kag + tokbase; K = qg  + tokbase; VT = vTg  + vtbase; O = xau + tokbase; }
  Q += (size_t)qt * 64 * 1024;
  O += (size_t)qt * 64 * 1024;

  int wq = wave * 16;
  bf16x8 qf0 = *(const bf16x8*)&Q[(size_t)(wq + r15) * 1024 + g*8];
  bf16x8 qf1 = *(const bf16x8*)&Q[(size_t)(wq + r15) * 1024 + 32 + g*8];

  int srow = tid >> 3, scol = (tid & 7) * 8;
  const u16* Kp  = K  + (size_t)srow * 1024 + scol;
  const u16* VTp = VT + (size_t)srow * 1024 + scol;
  u16x8 kr0 = *(const u16x8*)(Kp);
  u16x8 kr1 = *(const u16x8*)(Kp + (size_t)32 * 1024);
  u16x8 vr0 = *(const u16x8*)(VTp);
  u16x8 vr1 = *(const u16x8*)(VTp + (size_t)32 * 1024);

  float l = 0.0f;
  f32x4 acc[4] = {};
  bool gh = g >= 2, g0 = g & 1;
  const f32x4 zinit = {-32.f, -32.f, -32.f, -32.f};

  for (int j = 0; j < 16; ++j){
    __syncthreads();
    *(u16x8*)&Ks [SW(srow,      scol)] = kr0;
    *(u16x8*)&Ks [SW(srow + 32, scol)] = kr1;
    *(u16x8*)&VTs[SW(srow,      scol)] = vr0;
    *(u16x8*)&VTs[SW(srow + 32, scol)] = vr1;
    if (j < 15){
      const u16* Kn = Kp  + (size_t)(j + 1) * 64 * 1024;
      const u16* Vn = VTp + (j + 1) * 64;
      kr0 = *(const u16x8*)(Kn);
      kr1 = *(const u16x8*)(Kn + (size_t)32 * 1024);
      vr0 = *(const u16x8*)(Vn);
      vr1 = *(const u16x8*)(Vn + (size_t)32 * 1024);
    }
    __syncthreads();

    f32x4 sf[4];
    __builtin_amdgcn_s_setprio(1);
#pragma unroll
    for (int kvi = 0; kvi < 4; ++kvi){
      bf16x8 kf0 = *(const bf16x8*)&Ks[SW(kvi*16 + r15, g*8)];
      bf16x8 kf1 = *(const bf16x8*)&Ks[SW(kvi*16 + r15, 32 + g*8)];
      f32x4 z = MFMA16(kf0, qf0, zinit);
      z = MFMA16(kf1, qf1, z);
      sf[kvi] = z;
    }
    __builtin_amdgcn_s_setprio(0);

    float psum = 0.0f;
#pragma unroll
    for (int kvi = 0; kvi < 4; ++kvi)
#pragma unroll
      for (int r = 0; r < 4; ++r){
        float p = __builtin_amdgcn_exp2f(sf[kvi][r]);
        sf[kvi][r] = p; psum += p;
      }
    psum += __shfl_xor(psum, 16);
    psum += __shfl_xor(psum, 32);
    l += psum;

    bf16x8 pf0, pf1;
    exchP(sf[0], sf[1], sf[2], sf[3], gh, g0, pf0, pf1);

    __builtin_amdgcn_s_setprio(1);
#pragma unroll
    for (int nb = 0; nb < 4; ++nb){
      bf16x8 vf0 = *(const bf16x8*)&VTs[SW(nb*16 + r15, g*8)];
      acc[nb] = MFMA16(vf0, pf0, acc[nb]);
    }
#pragma unroll
    for (int nb = 0; nb < 4; ++nb){
      bf16x8 vf1 = *(const bf16x8*)&VTs[SW(nb*16 + r15, 32 + g*8)];
      acc[nb] = MFMA16(vf1, pf1, acc[nb]);
    }
    __builtin_amdgcn_s_setprio(0);
  }

  float inv = 1.0f / l;
  size_t orow = (size_t)(wq + r15) * 1024;
#pragma unroll
  for (int nb = 0; nb < 4; ++nb){
    u16x4 o;
    o.x = f2bf(acc[nb][0] * inv);
    o.y = f2bf(acc[nb][1] * inv);
    o.z = f2bf(acc[nb][2] * inv);
    o.w = f2bf(acc[nb][3] * inv);
    *(u16x4*)&O[orow + nb*16 + g*4] = o;
  }
}

extern "C" void kernel_launch(void* const* d_in, const int* in_sizes, int n_in,
                              void* d_out, int out_size, void* d_ws, size_t ws_size,
                              hipStream_t stream){
  const float* x    = (const float*)d_in[0];
  const float* xa   = (const float*)d_in[1];
  const float* lnw  = (const float*)d_in[2];
  const float* lnb  = (const float*)d_in[3];
  const float* Wq   = (const float*)d_in[4];
  const float* Wkv  = (const float*)d_in[5];
  const float* Wout = (const float*)d_in[6];
  float* out = (float*)d_out;
  char* ws = (char*)d_ws;
  const size_t MB = 1ull << 20;
  u16* xn  = (u16*)(ws);
  u16* xan = (u16*)(ws + 8*MB);
  u16* q   = (u16*)(ws + 16*MB);
  u16* vT  = (u16*)(ws + 24*MB);
  u16* ka  = (u16*)(ws + 32*MB);
  u16* vaT = (u16*)(ws + 40*MB);
  u16* xu  = (u16*)(ws + 48*MB);   // xu..xau contiguous -> M=8192 out-GEMM
  u16* xau = (u16*)(ws + 56*MB);
  u16* WqT = (u16*)(ws + 64*MB);
  u16* WkT = (u16*)(ws + 66*MB);
  u16* WvT = (u16*)(ws + 68*MB);
  u16* WoT = (u16*)(ws + 70*MB);
  dim3 blk(256);
  // fused prep: 8192 LN rows + 1024 transpose tiles in one launch
  prep<<<dim3(9216), blk, 0, stream>>>(x, xa, lnw, lnb, Wq, Wkv, Wout,
                                       xn, xan, WqT, WkT, WvT, WoT);
  // proj: quads 0:q, 1:vT(tr), 2:ka, 3:vaT(tr). 1-D 256 blocks, XCD-grouped.
  gemm256<256, 4, 0xA, u16><<<dim3(256), dim3(512), 0, stream>>>(
      xn, xn, xan, xan, WqT, WvT, WkT, WvT, q, vT, ka, vaT);
  flash<<<dim3(2048), blk, 0, stream>>>(q, vT, ka, vaT, xu, xau);
  // out: single M=8192 GEMM (xu||xau) @ WoT -> (out0||out1) f32. 256 blocks.
  gemm256<128, 1, 0, float><<<dim3(256), dim3(512), 0, stream>>>(
      xu, xu, xu, xu, WoT, WoT, WoT, WoT, out, out, out, out);
}

// Round 22
// 143.674 us; speedup vs baseline: 1.0109x; 1.0109x over previous
//
#include <hip/hip_runtime.h>
#include <hip/hip_bf16.h>

typedef unsigned short u16;
typedef unsigned int u32;
typedef __attribute__((ext_vector_type(4))) unsigned short u16x4;
typedef __attribute__((ext_vector_type(8))) unsigned short u16x8;
typedef __attribute__((ext_vector_type(8))) __bf16 bf16x8;
typedef __attribute__((ext_vector_type(4))) float f32x4;

__device__ __forceinline__ u16 f2bf(float f){
  unsigned u = __builtin_bit_cast(unsigned, f);
  u += 0x7FFFu + ((u >> 16) & 1u);
  return (u16)(u >> 16);
}

__device__ __forceinline__ u32 cvtpk(float lo, float hi){
  u32 r;
  asm("v_cvt_pk_bf16_f32 %0, %1, %2" : "=v"(r) : "v"(lo), "v"(hi));
  return r;
}

__device__ __forceinline__ void load_lds16(const void* g, void* l){
  __builtin_amdgcn_global_load_lds((const __attribute__((address_space(1))) unsigned*)g,
                                   (__attribute__((address_space(3))) unsigned*)l, 16, 0, 0);
}

__device__ __forceinline__ void storeC(float* p, float v){ *p = v; }
__device__ __forceinline__ void storeC(u16* p, float v){ *p = f2bf(v); }

// ---------------- fused prep: LN(x|xa)->bf16 (bid<8192) + 4 weight transposes ----
// Wq additionally scaled by log2(e): scores live in the exp2 domain (no-max softmax).
__global__ __launch_bounds__(256) void prep(const float* __restrict__ x, const float* __restrict__ xa,
                                            const float* __restrict__ w, const float* __restrict__ bb,
                                            const float* __restrict__ Wq, const float* __restrict__ Wkv,
                                            const float* __restrict__ Wout,
                                            u16* __restrict__ xn, u16* __restrict__ xan,
                                            u16* __restrict__ WqT, u16* __restrict__ WkT,
                                            u16* __restrict__ WvT, u16* __restrict__ WoT){
  __shared__ float tile[64][65];
  int bid = blockIdx.x, t = threadIdx.x;
  if (bid < 8192){
    int row = bid;
    const float* src; u16* dst;
    if (row < 4096){ src = x + (size_t)row * 1024; dst = xn + (size_t)row * 1024; }
    else { src = xa + (size_t)(row - 4096) * 1024; dst = xan + (size_t)(row - 4096) * 1024; }
    float4 v = ((const float4*)src)[t];
    float s = v.x + v.y + v.z + v.w;
    float ss = v.x*v.x + v.y*v.y + v.z*v.z + v.w*v.w;
#pragma unroll
    for (int o = 32; o > 0; o >>= 1){ s += __shfl_down(s, o); ss += __shfl_down(ss, o); }
    float* red = &tile[0][0];
    int wv = t >> 6;
    if ((t & 63) == 0){ red[wv] = s; red[wv + 4] = ss; }
    __syncthreads();
    if (t == 0){
      red[0] = red[0] + red[1] + red[2] + red[3];
      red[4] = red[4] + red[5] + red[6] + red[7];
    }
    __syncthreads();
    float mu = red[0] * (1.0f/1024.0f);
    float var = red[4] * (1.0f/1024.0f) - mu*mu;
    float rstd = rsqrtf(var + 1e-5f);
    float4 wv4 = ((const float4*)w)[t];
    float4 bv4 = ((const float4*)bb)[t];
    u16x4 o4;
    o4.x = f2bf((v.x - mu) * rstd * wv4.x + bv4.x);
    o4.y = f2bf((v.y - mu) * rstd * wv4.y + bv4.y);
    o4.z = f2bf((v.z - mu) * rstd * wv4.z + bv4.z);
    o4.w = f2bf((v.w - mu) * rstd * wv4.w + bv4.w);
    ((u16x4*)dst)[t] = o4;
    return;
  }
  int tt = bid - 8192;
  int z = tt >> 8, rem = tt & 255;
  int bx = rem & 15, by = rem >> 4;
  const float* in; u16* out; int ldin;
  switch (z){
    case 0:  in = Wq;         out = WqT; ldin = 1024; break;
    case 1:  in = Wkv;        out = WkT; ldin = 2048; break;
    case 2:  in = Wkv + 1024; out = WvT; ldin = 2048; break;
    default: in = Wout;       out = WoT; ldin = 1024; break;
  }
  float scl = (z == 0) ? 1.44269504f : 1.0f;
  int tr = by * 64, tc = bx * 64;
  int r0 = t >> 4, c0 = (t & 15) * 4;
#pragma unroll
  for (int i = 0; i < 4; ++i){
    int r = r0 + i * 16;
    const float4 val = *(const float4*)&in[(size_t)(tr + r) * ldin + tc + c0];
    tile[r][c0] = val.x; tile[r][c0+1] = val.y; tile[r][c0+2] = val.z; tile[r][c0+3] = val.w;
  }
  __syncthreads();
#pragma unroll
  for (int i = 0; i < 4; ++i){
    int n = r0 + i * 16;
    u16x4 o4;
    o4.x = f2bf(tile[c0+0][n] * scl); o4.y = f2bf(tile[c0+1][n] * scl);
    o4.z = f2bf(tile[c0+2][n] * scl); o4.w = f2bf(tile[c0+3][n] * scl);
    *(u16x4*)&out[(size_t)(tc + n) * 1024 + tr + c0] = o4;
  }
}

// ---------------- BMx256 GEMM, BK=64, 8 waves, dbuf, counted vmcnt ----------------
// R17 epilogue: transposed quads pack r=0..3 (consecutive tokens) into one
// u16x4 store -> 4x fewer store instrs, 4x smaller cacheline footprint.
template<int BM, int NQ, int TMASK, typename OutT>
__global__ __launch_bounds__(512, 2) void gemm256(
    const u16* __restrict__ A0, const u16* __restrict__ A1,
    const u16* __restrict__ A2, const u16* __restrict__ A3,
    const u16* __restrict__ B0, const u16* __restrict__ B1,
    const u16* __restrict__ B2, const u16* __restrict__ B3,
    OutT* __restrict__ C0, OutT* __restrict__ C1,
    OutT* __restrict__ C2, OutT* __restrict__ C3){
  constexpr int AI = BM / 64;
  constexpr int FI = BM / 32;
  constexpr int MT = (NQ == 4) ? 16 : 64;
  __shared__ u16 SA[2][BM * 64];
  __shared__ u16 SB[2][16384];
  int tid = threadIdx.x, lane = tid & 63, wave = tid >> 6;
  int g = lane >> 4, r15 = lane & 15;
  int id = blockIdx.x;
  int r8 = id & 7, k = id >> 3;
  int gm = (k >> 2) * 8 + r8;
  int ntile = k & 3;
  int quad = gm / MT;
  int mbase = (gm % MT) * BM, nbase = ntile * 256;
  const u16* A = quad==0?A0:quad==1?A1:quad==2?A2:A3;
  const u16* B = quad==0?B0:quad==1?B1:quad==2?B2:B3;
  OutT* C      = quad==0?C0:quad==1?C1:quad==2?C2:C3;
  int wr = wave >> 2, wc = wave & 3;
  int rsub = lane >> 3;
  int slo  = (lane & 7) ^ ((lane >> 3) & 7);
  int sw8  = (r15 & 7) << 3;
  f32x4 acc[FI][4] = {};

#define STG(kt, b) { \
  int ko = (kt) * 64; \
  _Pragma("unroll") \
  for (int i = 0; i < AI; ++i){ \
    int row = i*64 + wave*8 + rsub; \
    load_lds16(A + (size_t)(mbase + row)*1024 + ko + slo*8, &SA[b][(i*512 + wave*64)*8]); \
  } \
  _Pragma("unroll") \
  for (int i = 0; i < 4; ++i){ \
    int row = i*64 + wave*8 + rsub; \
    load_lds16(B + (size_t)(nbase + row)*1024 + ko + slo*8, &SB[b][(i*512 + wave*64)*8]); \
  } }

  STG(0, 0);
  for (int t = 0; t < 16; ++t){
    int b = t & 1;
    if (t < 15){
      STG(t + 1, b ^ 1);
      if constexpr (AI == 4) asm volatile("s_waitcnt vmcnt(8)" ::: "memory");
      else                   asm volatile("s_waitcnt vmcnt(6)" ::: "memory");
    } else {
      asm volatile("s_waitcnt vmcnt(0)" ::: "memory");
    }
    __builtin_amdgcn_s_barrier();
    __builtin_amdgcn_sched_barrier(0);
    const u16* Al = &SA[b][0];
    const u16* Bl = &SB[b][0];
#pragma unroll
    for (int ks = 0; ks < 2; ++ks){
      bf16x8 af[FI], bfr[4];
#pragma unroll
      for (int fi = 0; fi < FI; ++fi)
        af[fi] = *(const bf16x8*)&Al[(wr*(FI*16) + fi*16 + r15)*64 + ((ks*32 + g*8) ^ sw8)];
#pragma unroll
      for (int fj = 0; fj < 4; ++fj)
        bfr[fj] = *(const bf16x8*)&Bl[(wc*64 + fj*16 + r15)*64 + ((ks*32 + g*8) ^ sw8)];
#pragma unroll
      for (int fi = 0; fi < FI; ++fi)
#pragma unroll
        for (int fj = 0; fj < 4; ++fj)
          acc[fi][fj] = __builtin_amdgcn_mfma_f32_16x16x32_bf16(af[fi], bfr[fj], acc[fi][fj], 0, 0, 0);
    }
    __builtin_amdgcn_s_barrier();
  }
#undef STG

  bool tr = (TMASK >> quad) & 1;
#pragma unroll
  for (int fi = 0; fi < FI; ++fi)
#pragma unroll
    for (int fj = 0; fj < 4; ++fj){
      int colb = nbase + wc*64 + fj*16 + r15;
      int row0 = mbase + wr*(FI*16) + fi*16 + g*4;
      if constexpr (TMASK != 0){
        if (tr){
          // vT[bh][d][token]: r = consecutive tokens -> one packed 8B store
          int bb = row0 >> 10, token = row0 & 1023;   // rows 0..3 same bb (mbase % 256 == 0)
          int hh = colb >> 6, dd = colb & 63;
          u16x4 o;
          o.x = f2bf(acc[fi][fj][0]); o.y = f2bf(acc[fi][fj][1]);
          o.z = f2bf(acc[fi][fj][2]); o.w = f2bf(acc[fi][fj][3]);
          *(u16x4*)((u16*)C + ((size_t)((bb << 4) + hh) * 64 + dd) * 1024 + token) = o;
          continue;
        }
      }
#pragma unroll
      for (int r = 0; r < 4; ++r)
        storeC(&C[(size_t)(row0 + r) * 1024 + colb], acc[fi][fj][r]);
    }
}

// ---------------- flash attention: QBLK=16 body (R21-passing) + R8-passing raw-barrier
// scheme: barrier1 = raw s_barrier (WAR-safe: each wave's ds_reads completed before its
// consuming MFMAs); barrier2 = lgkmcnt(0) + s_barrier, vmcnt RIDES across barriers so
// the kr/vr prefetch stays in flight through the compute phase (T4/T14).
// 1D grid 2048, XCD-bijective decode. No-max exp2 softmax (Wq pre-scaled by log2e).
#define SW(row, col) ((row) * 64 + ((col) ^ (((row) & 7) << 3)))

__device__ __forceinline__ void exchP(const f32x4& s0, const f32x4& s1,
                                      const f32x4& s2, const f32x4& s3,
                                      bool gh, bool g0, bf16x8& pf0, bf16x8& pf1){
  u32 pk00 = cvtpk(s0[0], s0[1]), pk01 = cvtpk(s0[2], s0[3]);
  u32 pk10 = cvtpk(s1[0], s1[1]), pk11 = cvtpk(s1[2], s1[3]);
  u32 pk20 = cvtpk(s2[0], s2[1]), pk21 = cvtpk(s2[2], s2[3]);
  u32 pk30 = cvtpk(s3[0], s3[1]), pk31 = cvtpk(s3[2], s3[3]);
  u32 c0 = gh ? pk10 : pk00, c1 = gh ? pk11 : pk01;
  u32 d0 = gh ? pk00 : pk10, d1 = gh ? pk01 : pk11;
  u32 s1a = __shfl_xor((int)c0, 16), s1b = __shfl_xor((int)c1, 16);
  u32 s2a = __shfl_xor((int)d0, 32), s2b = __shfl_xor((int)d1, 32);
  u32 s3a = __shfl_xor((int)d0, 48), s3b = __shfl_xor((int)d1, 48);
  union UB { u32 w[4]; bf16x8 v; } ub0, ub1;
  ub0.w[0] = gh ? (g0 ? s1a : s2a) : (g0 ? s3a : c0);
  ub0.w[1] = gh ? (g0 ? s1b : s2b) : (g0 ? s3b : c1);
  ub0.w[2] = gh ? (g0 ? c0 : s3a) : (g0 ? s2a : s1a);
  ub0.w[3] = gh ? (g0 ? c1 : s3b) : (g0 ? s2b : s1b);
  u32 e0 = gh ? pk30 : pk20, e1 = gh ? pk31 : pk21;
  u32 f0 = gh ? pk20 : pk30, f1 = gh ? pk21 : pk31;
  u32 t1a = __shfl_xor((int)e0, 16), t1b = __shfl_xor((int)e1, 16);
  u32 t2a = __shfl_xor((int)f0, 32), t2b = __shfl_xor((int)f1, 32);
  u32 t3a = __shfl_xor((int)f0, 48), t3b = __shfl_xor((int)f1, 48);
  ub1.w[0] = gh ? (g0 ? t1a : t2a) : (g0 ? t3a : e0);
  ub1.w[1] = gh ? (g0 ? t1b : t2b) : (g0 ? t3b : e1);
  ub1.w[2] = gh ? (g0 ? e0 : t3a) : (g0 ? t2a : t1a);
  ub1.w[3] = gh ? (g0 ? e1 : t3b) : (g0 ? t2b : t1b);
  pf0 = ub0.v; pf1 = ub1.v;
}

#define MFMA16(a, b, c) __builtin_amdgcn_mfma_f32_16x16x32_bf16(a, b, c, 0, 0, 0)

__global__ __launch_bounds__(256) void flash(const u16* __restrict__ qg, const u16* __restrict__ vTg,
                                             const u16* __restrict__ kag, const u16* __restrict__ vaTg,
                                             u16* __restrict__ xu, u16* __restrict__ xau){
  __shared__ u16 Ks[4096], VTs[4096];
  int tid = threadIdx.x, lane = tid & 63, wave = tid >> 6, g = lane >> 4, r15 = lane & 15;
  int b = blockIdx.x;
  int xcd = b & 7, idx = b >> 3;
  int qt = idx & 15;
  int pair = xcd * 16 + (idx >> 4);
  int bh = pair & 63, dir = pair >> 6;
  size_t tokbase = ((size_t)(bh >> 4)) * 1048576 + (size_t)(bh & 15) * 64;
  size_t vtbase  = (size_t)bh << 16;
  const u16 *Q, *K, *VT; u16* O;
  if (dir == 0){ Q = qg + tokbase;  K = kag + tokbase; VT = vaTg + vtbase; O = xu  + tokbase; }
  else         { Q = kag + tokbase; K = qg  + tokbase; VT = vTg  + vtbase; O = xau + tokbase; }
  Q += (size_t)qt * 64 * 1024;
  O += (size_t)qt * 64 * 1024;

  int wq = wave * 16;
  bf16x8 qf0 = *(const bf16x8*)&Q[(size_t)(wq + r15) * 1024 + g*8];
  bf16x8 qf1 = *(const bf16x8*)&Q[(size_t)(wq + r15) * 1024 + 32 + g*8];

  int srow = tid >> 3, scol = (tid & 7) * 8;
  const u16* Kp  = K  + (size_t)srow * 1024 + scol;
  const u16* VTp = VT + (size_t)srow * 1024 + scol;
  u16x8 kr0 = *(const u16x8*)(Kp);
  u16x8 kr1 = *(const u16x8*)(Kp + (size_t)32 * 1024);
  u16x8 vr0 = *(const u16x8*)(VTp);
  u16x8 vr1 = *(const u16x8*)(VTp + (size_t)32 * 1024);

  float l = 0.0f;
  f32x4 acc[4] = {};
  bool gh = g >= 2, g0 = g & 1;
  const f32x4 zinit = {-32.f, -32.f, -32.f, -32.f};

  for (int j = 0; j < 16; ++j){
    __builtin_amdgcn_sched_barrier(0);
    __builtin_amdgcn_s_barrier();       // WAR: all waves' LDS reads of iter j-1 done
    __builtin_amdgcn_sched_barrier(0);  //      (data-dep lgkm waits preceded their MFMAs)
    *(u16x8*)&Ks [SW(srow,      scol)] = kr0;   // compiler inserts vmcnt wait for kr/vr
    *(u16x8*)&Ks [SW(srow + 32, scol)] = kr1;
    *(u16x8*)&VTs[SW(srow,      scol)] = vr0;
    *(u16x8*)&VTs[SW(srow + 32, scol)] = vr1;
    if (j < 15){                        // T14: issue next tile's loads; they stay in
      const u16* Kn = Kp  + (size_t)(j + 1) * 64 * 1024;  // flight across both barriers
      const u16* Vn = VTp + (j + 1) * 64;
      kr0 = *(const u16x8*)(Kn);
      kr1 = *(const u16x8*)(Kn + (size_t)32 * 1024);
      vr0 = *(const u16x8*)(Vn);
      vr1 = *(const u16x8*)(Vn + (size_t)32 * 1024);
    }
    asm volatile("s_waitcnt lgkmcnt(0)" ::: "memory");  // ds_writes committed (vmcnt rides)
    __builtin_amdgcn_sched_barrier(0);
    __builtin_amdgcn_s_barrier();       // staging visible to all waves
    __builtin_amdgcn_sched_barrier(0);

    f32x4 sf[4];
    __builtin_amdgcn_s_setprio(1);
#pragma unroll
    for (int kvi = 0; kvi < 4; ++kvi){
      bf16x8 kf0 = *(const bf16x8*)&Ks[SW(kvi*16 + r15, g*8)];
      bf16x8 kf1 = *(const bf16x8*)&Ks[SW(kvi*16 + r15, 32 + g*8)];
      f32x4 z = MFMA16(kf0, qf0, zinit);
      z = MFMA16(kf1, qf1, z);
      sf[kvi] = z;
    }
    __builtin_amdgcn_s_setprio(0);

    float psum = 0.0f;
#pragma unroll
    for (int kvi = 0; kvi < 4; ++kvi)
#pragma unroll
      for (int r = 0; r < 4; ++r){
        float p = __builtin_amdgcn_exp2f(sf[kvi][r]);
        sf[kvi][r] = p; psum += p;
      }
    psum += __shfl_xor(psum, 16);
    psum += __shfl_xor(psum, 32);
    l += psum;

    bf16x8 pf0, pf1;
    exchP(sf[0], sf[1], sf[2], sf[3], gh, g0, pf0, pf1);

    __builtin_amdgcn_s_setprio(1);
#pragma unroll
    for (int nb = 0; nb < 4; ++nb){
      bf16x8 vf0 = *(const bf16x8*)&VTs[SW(nb*16 + r15, g*8)];
      acc[nb] = MFMA16(vf0, pf0, acc[nb]);
    }
#pragma unroll
    for (int nb = 0; nb < 4; ++nb){
      bf16x8 vf1 = *(const bf16x8*)&VTs[SW(nb*16 + r15, 32 + g*8)];
      acc[nb] = MFMA16(vf1, pf1, acc[nb]);
    }
    __builtin_amdgcn_s_setprio(0);
  }

  float inv = 1.0f / l;
  size_t orow = (size_t)(wq + r15) * 1024;
#pragma unroll
  for (int nb = 0; nb < 4; ++nb){
    u16x4 o;
    o.x = f2bf(acc[nb][0] * inv);
    o.y = f2bf(acc[nb][1] * inv);
    o.z = f2bf(acc[nb][2] * inv);
    o.w = f2bf(acc[nb][3] * inv);
    *(u16x4*)&O[orow + nb*16 + g*4] = o;
  }
}

extern "C" void kernel_launch(void* const* d_in, const int* in_sizes, int n_in,
                              void* d_out, int out_size, void* d_ws, size_t ws_size,
                              hipStream_t stream){
  const float* x    = (const float*)d_in[0];
  const float* xa   = (const float*)d_in[1];
  const float* lnw  = (const float*)d_in[2];
  const float* lnb  = (const float*)d_in[3];
  const float* Wq   = (const float*)d_in[4];
  const float* Wkv  = (const float*)d_in[5];
  const float* Wout = (const float*)d_in[6];
  float* out = (float*)d_out;
  char* ws = (char*)d_ws;
  const size_t MB = 1ull << 20;
  u16* xn  = (u16*)(ws);
  u16* xan = (u16*)(ws + 8*MB);
  u16* q   = (u16*)(ws + 16*MB);
  u16* vT  = (u16*)(ws + 24*MB);
  u16* ka  = (u16*)(ws + 32*MB);
  u16* vaT = (u16*)(ws + 40*MB);
  u16* xu  = (u16*)(ws + 48*MB);   // xu..xau contiguous -> M=8192 out-GEMM
  u16* xau = (u16*)(ws + 56*MB);
  u16* WqT = (u16*)(ws + 64*MB);
  u16* WkT = (u16*)(ws + 66*MB);
  u16* WvT = (u16*)(ws + 68*MB);
  u16* WoT = (u16*)(ws + 70*MB);
  dim3 blk(256);
  // fused prep: 8192 LN rows + 1024 transpose tiles in one launch
  prep<<<dim3(9216), blk, 0, stream>>>(x, xa, lnw, lnb, Wq, Wkv, Wout,
                                       xn, xan, WqT, WkT, WvT, WoT);
  // proj: quads 0:q, 1:vT(tr), 2:ka, 3:vaT(tr). 1-D 256 blocks, XCD-grouped.
  gemm256<256, 4, 0xA, u16><<<dim3(256), dim3(512), 0, stream>>>(
      xn, xn, xan, xan, WqT, WvT, WkT, WvT, q, vT, ka, vaT);
  flash<<<dim3(2048), blk, 0, stream>>>(q, vT, ka, vaT, xu, xau);
  // out: single M=8192 GEMM (xu||xau) @ WoT -> (out0||out1) f32. 256 blocks.
  gemm256<128, 1, 0, float><<<dim3(256), dim3(512), 0, stream>>>(
      xu, xu, xu, xu, WoT, WoT, WoT, WoT, out, out, out, out);
}

// Round 23
// 141.008 us; speedup vs baseline: 1.0300x; 1.0189x over previous
//
#include <hip/hip_runtime.h>
#include <hip/hip_bf16.h>

typedef unsigned short u16;
typedef unsigned int u32;
typedef __attribute__((ext_vector_type(4))) unsigned short u16x4;
typedef __attribute__((ext_vector_type(8))) unsigned short u16x8;
typedef __attribute__((ext_vector_type(8))) __bf16 bf16x8;
typedef __attribute__((ext_vector_type(4))) float f32x4;

__device__ __forceinline__ u16 f2bf(float f){
  unsigned u = __builtin_bit_cast(unsigned, f);
  u += 0x7FFFu + ((u >> 16) & 1u);
  return (u16)(u >> 16);
}

__device__ __forceinline__ u32 cvtpk(float lo, float hi){
  u32 r;
  asm("v_cvt_pk_bf16_f32 %0, %1, %2" : "=v"(r) : "v"(lo), "v"(hi));
  return r;
}

__device__ __forceinline__ void load_lds16(const void* g, void* l){
  __builtin_amdgcn_global_load_lds((const __attribute__((address_space(1))) unsigned*)g,
                                   (__attribute__((address_space(3))) unsigned*)l, 16, 0, 0);
}

__device__ __forceinline__ void storeC(float* p, float v){ *p = v; }
__device__ __forceinline__ void storeC(u16* p, float v){ *p = f2bf(v); }

// ---------------- fused prep: LN(x|xa)->bf16 (bid<8192) + 4 weight transposes ----
// Wq additionally scaled by log2(e): scores live in the exp2 domain (no-max softmax).
__global__ __launch_bounds__(256) void prep(const float* __restrict__ x, const float* __restrict__ xa,
                                            const float* __restrict__ w, const float* __restrict__ bb,
                                            const float* __restrict__ Wq, const float* __restrict__ Wkv,
                                            const float* __restrict__ Wout,
                                            u16* __restrict__ xn, u16* __restrict__ xan,
                                            u16* __restrict__ WqT, u16* __restrict__ WkT,
                                            u16* __restrict__ WvT, u16* __restrict__ WoT){
  __shared__ float tile[64][65];
  int bid = blockIdx.x, t = threadIdx.x;
  if (bid < 8192){
    int row = bid;
    const float* src; u16* dst;
    if (row < 4096){ src = x + (size_t)row * 1024; dst = xn + (size_t)row * 1024; }
    else { src = xa + (size_t)(row - 4096) * 1024; dst = xan + (size_t)(row - 4096) * 1024; }
    float4 v = ((const float4*)src)[t];
    float s = v.x + v.y + v.z + v.w;
    float ss = v.x*v.x + v.y*v.y + v.z*v.z + v.w*v.w;
#pragma unroll
    for (int o = 32; o > 0; o >>= 1){ s += __shfl_down(s, o); ss += __shfl_down(ss, o); }
    float* red = &tile[0][0];
    int wv = t >> 6;
    if ((t & 63) == 0){ red[wv] = s; red[wv + 4] = ss; }
    __syncthreads();
    if (t == 0){
      red[0] = red[0] + red[1] + red[2] + red[3];
      red[4] = red[4] + red[5] + red[6] + red[7];
    }
    __syncthreads();
    float mu = red[0] * (1.0f/1024.0f);
    float var = red[4] * (1.0f/1024.0f) - mu*mu;
    float rstd = rsqrtf(var + 1e-5f);
    float4 wv4 = ((const float4*)w)[t];
    float4 bv4 = ((const float4*)bb)[t];
    u16x4 o4;
    o4.x = f2bf((v.x - mu) * rstd * wv4.x + bv4.x);
    o4.y = f2bf((v.y - mu) * rstd * wv4.y + bv4.y);
    o4.z = f2bf((v.z - mu) * rstd * wv4.z + bv4.z);
    o4.w = f2bf((v.w - mu) * rstd * wv4.w + bv4.w);
    ((u16x4*)dst)[t] = o4;
    return;
  }
  int tt = bid - 8192;
  int z = tt >> 8, rem = tt & 255;
  int bx = rem & 15, by = rem >> 4;
  const float* in; u16* out; int ldin;
  switch (z){
    case 0:  in = Wq;         out = WqT; ldin = 1024; break;
    case 1:  in = Wkv;        out = WkT; ldin = 2048; break;
    case 2:  in = Wkv + 1024; out = WvT; ldin = 2048; break;
    default: in = Wout;       out = WoT; ldin = 1024; break;
  }
  float scl = (z == 0) ? 1.44269504f : 1.0f;
  int tr = by * 64, tc = bx * 64;
  int r0 = t >> 4, c0 = (t & 15) * 4;
#pragma unroll
  for (int i = 0; i < 4; ++i){
    int r = r0 + i * 16;
    const float4 val = *(const float4*)&in[(size_t)(tr + r) * ldin + tc + c0];
    tile[r][c0] = val.x; tile[r][c0+1] = val.y; tile[r][c0+2] = val.z; tile[r][c0+3] = val.w;
  }
  __syncthreads();
#pragma unroll
  for (int i = 0; i < 4; ++i){
    int n = r0 + i * 16;
    u16x4 o4;
    o4.x = f2bf(tile[c0+0][n] * scl); o4.y = f2bf(tile[c0+1][n] * scl);
    o4.z = f2bf(tile[c0+2][n] * scl); o4.w = f2bf(tile[c0+3][n] * scl);
    *(u16x4*)&out[(size_t)(tc + n) * 1024 + tr + c0] = o4;
  }
}

// ---------------- BMx256 GEMM, BK=64, 8 waves, dbuf, counted vmcnt ----------------
// R17 epilogue: transposed quads pack r=0..3 (consecutive tokens) into one
// u16x4 store -> 4x fewer store instrs, 4x smaller cacheline footprint.
template<int BM, int NQ, int TMASK, typename OutT>
__global__ __launch_bounds__(512, 2) void gemm256(
    const u16* __restrict__ A0, const u16* __restrict__ A1,
    const u16* __restrict__ A2, const u16* __restrict__ A3,
    const u16* __restrict__ B0, const u16* __restrict__ B1,
    const u16* __restrict__ B2, const u16* __restrict__ B3,
    OutT* __restrict__ C0, OutT* __restrict__ C1,
    OutT* __restrict__ C2, OutT* __restrict__ C3){
  constexpr int AI = BM / 64;
  constexpr int FI = BM / 32;
  constexpr int MT = (NQ == 4) ? 16 : 64;
  __shared__ u16 SA[2][BM * 64];
  __shared__ u16 SB[2][16384];
  int tid = threadIdx.x, lane = tid & 63, wave = tid >> 6;
  int g = lane >> 4, r15 = lane & 15;
  int id = blockIdx.x;
  int r8 = id & 7, k = id >> 3;
  int gm = (k >> 2) * 8 + r8;
  int ntile = k & 3;
  int quad = gm / MT;
  int mbase = (gm % MT) * BM, nbase = ntile * 256;
  const u16* A = quad==0?A0:quad==1?A1:quad==2?A2:A3;
  const u16* B = quad==0?B0:quad==1?B1:quad==2?B2:B3;
  OutT* C      = quad==0?C0:quad==1?C1:quad==2?C2:C3;
  int wr = wave >> 2, wc = wave & 3;
  int rsub = lane >> 3;
  int slo  = (lane & 7) ^ ((lane >> 3) & 7);
  int sw8  = (r15 & 7) << 3;
  f32x4 acc[FI][4] = {};

#define STG(kt, b) { \
  int ko = (kt) * 64; \
  _Pragma("unroll") \
  for (int i = 0; i < AI; ++i){ \
    int row = i*64 + wave*8 + rsub; \
    load_lds16(A + (size_t)(mbase + row)*1024 + ko + slo*8, &SA[b][(i*512 + wave*64)*8]); \
  } \
  _Pragma("unroll") \
  for (int i = 0; i < 4; ++i){ \
    int row = i*64 + wave*8 + rsub; \
    load_lds16(B + (size_t)(nbase + row)*1024 + ko + slo*8, &SB[b][(i*512 + wave*64)*8]); \
  } }

  STG(0, 0);
  for (int t = 0; t < 16; ++t){
    int b = t & 1;
    if (t < 15){
      STG(t + 1, b ^ 1);
      if constexpr (AI == 4) asm volatile("s_waitcnt vmcnt(8)" ::: "memory");
      else                   asm volatile("s_waitcnt vmcnt(6)" ::: "memory");
    } else {
      asm volatile("s_waitcnt vmcnt(0)" ::: "memory");
    }
    __builtin_amdgcn_s_barrier();
    __builtin_amdgcn_sched_barrier(0);
    const u16* Al = &SA[b][0];
    const u16* Bl = &SB[b][0];
#pragma unroll
    for (int ks = 0; ks < 2; ++ks){
      bf16x8 af[FI], bfr[4];
#pragma unroll
      for (int fi = 0; fi < FI; ++fi)
        af[fi] = *(const bf16x8*)&Al[(wr*(FI*16) + fi*16 + r15)*64 + ((ks*32 + g*8) ^ sw8)];
#pragma unroll
      for (int fj = 0; fj < 4; ++fj)
        bfr[fj] = *(const bf16x8*)&Bl[(wc*64 + fj*16 + r15)*64 + ((ks*32 + g*8) ^ sw8)];
#pragma unroll
      for (int fi = 0; fi < FI; ++fi)
#pragma unroll
        for (int fj = 0; fj < 4; ++fj)
          acc[fi][fj] = __builtin_amdgcn_mfma_f32_16x16x32_bf16(af[fi], bfr[fj], acc[fi][fj], 0, 0, 0);
    }
    __builtin_amdgcn_s_barrier();
  }
#undef STG

  bool tr = (TMASK >> quad) & 1;
#pragma unroll
  for (int fi = 0; fi < FI; ++fi)
#pragma unroll
    for (int fj = 0; fj < 4; ++fj){
      int colb = nbase + wc*64 + fj*16 + r15;
      int row0 = mbase + wr*(FI*16) + fi*16 + g*4;
      if constexpr (TMASK != 0){
        if (tr){
          // vT[bh][d][token]: r = consecutive tokens -> one packed 8B store
          int bb = row0 >> 10, token = row0 & 1023;   // rows 0..3 same bb (mbase % 256 == 0)
          int hh = colb >> 6, dd = colb & 63;
          u16x4 o;
          o.x = f2bf(acc[fi][fj][0]); o.y = f2bf(acc[fi][fj][1]);
          o.z = f2bf(acc[fi][fj][2]); o.w = f2bf(acc[fi][fj][3]);
          *(u16x4*)((u16*)C + ((size_t)((bb << 4) + hh) * 64 + dd) * 1024 + token) = o;
          continue;
        }
      }
#pragma unroll
      for (int r = 0; r < 4; ++r)
        storeC(&C[(size_t)(row0 + r) * 1024 + colb], acc[fi][fj][r]);
    }
}

// ---------------- flash attention: single-buffer global_load_lds staging ----------
// 1D grid 2048, XCD-bijective decode. 256 thr, 4 waves x 16 q-rows.
// 16 KB LDS (8 blocks/CU TLP), staging via global_load_lds (pre-swizzled source,
// linear dest), vmcnt(0)+barrier per tile; bottom barrier of iter j-1 guards iter
// j's staging writes. Deferred-l epilogue. No-max exp2 softmax (Wq pre-scaled).
#define SW(row, col) ((row) * 64 + ((col) ^ (((row) & 7) << 3)))

__device__ __forceinline__ void exchP(const f32x4& s0, const f32x4& s1,
                                      const f32x4& s2, const f32x4& s3,
                                      bool gh, bool g0, bf16x8& pf0, bf16x8& pf1){
  u32 pk00 = cvtpk(s0[0], s0[1]), pk01 = cvtpk(s0[2], s0[3]);
  u32 pk10 = cvtpk(s1[0], s1[1]), pk11 = cvtpk(s1[2], s1[3]);
  u32 pk20 = cvtpk(s2[0], s2[1]), pk21 = cvtpk(s2[2], s2[3]);
  u32 pk30 = cvtpk(s3[0], s3[1]), pk31 = cvtpk(s3[2], s3[3]);
  u32 c0 = gh ? pk10 : pk00, c1 = gh ? pk11 : pk01;
  u32 d0 = gh ? pk00 : pk10, d1 = gh ? pk01 : pk11;
  u32 s1a = __shfl_xor((int)c0, 16), s1b = __shfl_xor((int)c1, 16);
  u32 s2a = __shfl_xor((int)d0, 32), s2b = __shfl_xor((int)d1, 32);
  u32 s3a = __shfl_xor((int)d0, 48), s3b = __shfl_xor((int)d1, 48);
  union UB { u32 w[4]; bf16x8 v; } ub0, ub1;
  ub0.w[0] = gh ? (g0 ? s1a : s2a) : (g0 ? s3a : c0);
  ub0.w[1] = gh ? (g0 ? s1b : s2b) : (g0 ? s3b : c1);
  ub0.w[2] = gh ? (g0 ? c0 : s3a) : (g0 ? s2a : s1a);
  ub0.w[3] = gh ? (g0 ? c1 : s3b) : (g0 ? s2b : s1b);
  u32 e0 = gh ? pk30 : pk20, e1 = gh ? pk31 : pk21;
  u32 f0 = gh ? pk20 : pk30, f1 = gh ? pk21 : pk31;
  u32 t1a = __shfl_xor((int)e0, 16), t1b = __shfl_xor((int)e1, 16);
  u32 t2a = __shfl_xor((int)f0, 32), t2b = __shfl_xor((int)f1, 32);
  u32 t3a = __shfl_xor((int)f0, 48), t3b = __shfl_xor((int)f1, 48);
  ub1.w[0] = gh ? (g0 ? t1a : t2a) : (g0 ? t3a : e0);
  ub1.w[1] = gh ? (g0 ? t1b : t2b) : (g0 ? t3b : e1);
  ub1.w[2] = gh ? (g0 ? e0 : t3a) : (g0 ? t2a : t1a);
  ub1.w[3] = gh ? (g0 ? e1 : t3b) : (g0 ? t2b : t1b);
  pf0 = ub0.v; pf1 = ub1.v;
}

#define MFMA16(a, b, c) __builtin_amdgcn_mfma_f32_16x16x32_bf16(a, b, c, 0, 0, 0)

__global__ __launch_bounds__(256) void flash(const u16* __restrict__ qg, const u16* __restrict__ vTg,
                                             const u16* __restrict__ kag, const u16* __restrict__ vaTg,
                                             u16* __restrict__ xu, u16* __restrict__ xau){
  __shared__ u16 Ks[4096], VTs[4096];
  int tid = threadIdx.x, lane = tid & 63, wave = tid >> 6, g = lane >> 4, r15 = lane & 15;
  int b = blockIdx.x;
  int xcd = b & 7, idx = b >> 3;
  int qt = idx & 15;
  int pair = xcd * 16 + (idx >> 4);
  int bh = pair & 63, dir = pair >> 6;
  size_t tokbase = ((size_t)(bh >> 4)) * 1048576 + (size_t)(bh & 15) * 64;
  size_t vtbase  = (size_t)bh << 16;
  const u16 *Q, *K, *VT; u16* O;
  if (dir == 0){ Q = qg + tokbase;  K = kag + tokbase; VT = vaTg + vtbase; O = xu  + tokbase; }
  else         { Q = kag + tokbase; K = qg  + tokbase; VT = vTg  + vtbase; O = xau + tokbase; }
  Q += (size_t)qt * 64 * 1024;
  O += (size_t)qt * 64 * 1024;

  int wq = wave * 16;
  bf16x8 qf0 = *(const bf16x8*)&Q[(size_t)(wq + r15) * 1024 + g*8];
  bf16x8 qf1 = *(const bf16x8*)&Q[(size_t)(wq + r15) * 1024 + 32 + g*8];

  // staging source (pre-swizzled): row = wave*8 + i*32 + rl, chunk = (lane&7)^rl
  // (row&7 == rl since wave*8 and i*32 are 0 mod 8); LDS dest linear.
  int rl = lane >> 3;
  int ch = (lane & 7) ^ rl;
  const u16* Kb = K  + (size_t)(wave*8 + rl) * 1024 + ch*8;
  const u16* Vb = VT + (size_t)(wave*8 + rl) * 1024 + ch*8;

#define FSTG(j) { \
  load_lds16(Kb + (size_t)(j)*65536,                 &Ks [(wave*8)*64]); \
  load_lds16(Kb + (size_t)(j)*65536 + 32*1024,       &Ks [(wave*8 + 32)*64]); \
  load_lds16(Vb + (j)*64,                            &VTs[(wave*8)*64]); \
  load_lds16(Vb + (j)*64 + (size_t)32*1024,          &VTs[(wave*8 + 32)*64]); \
}

  float pl = 0.0f;                      // per-lane l partial; cross-g reduce deferred
  f32x4 acc[4] = {};
  bool gh = g >= 2, g0 = g & 1;
  const f32x4 zinit = {-32.f, -32.f, -32.f, -32.f};

  for (int j = 0; j < 16; ++j){
    FSTG(j);                            // safe: prev iter's bottom barrier passed
    asm volatile("s_waitcnt vmcnt(0)" ::: "memory");
    __builtin_amdgcn_s_barrier();       // tile j visible to all waves
    __builtin_amdgcn_sched_barrier(0);

    // S' - 32 = K Q^T + (-32): rows kv = 16*kvi + 4g + reg, col q = r15
    f32x4 sf[4];
    __builtin_amdgcn_s_setprio(1);
#pragma unroll
    for (int kvi = 0; kvi < 4; ++kvi){
      bf16x8 kf0 = *(const bf16x8*)&Ks[SW(kvi*16 + r15, g*8)];
      bf16x8 kf1 = *(const bf16x8*)&Ks[SW(kvi*16 + r15, 32 + g*8)];
      f32x4 z = MFMA16(kf0, qf0, zinit);
      z = MFMA16(kf1, qf1, z);
      sf[kvi] = z;
    }
    __builtin_amdgcn_s_setprio(0);

    // P = exp2(S' - 32); per-lane partial sum only
#pragma unroll
    for (int kvi = 0; kvi < 4; ++kvi)
#pragma unroll
      for (int r = 0; r < 4; ++r){
        float p = __builtin_amdgcn_exp2f(sf[kvi][r]);
        sf[kvi][r] = p; pl += p;
      }

    bf16x8 pf0, pf1;
    exchP(sf[0], sf[1], sf[2], sf[3], gh, g0, pf0, pf1);

    // PV: out^T[d][q] += V^T[d][kv] * P^T
    __builtin_amdgcn_s_setprio(1);
#pragma unroll
    for (int nb = 0; nb < 4; ++nb){
      bf16x8 vf0 = *(const bf16x8*)&VTs[SW(nb*16 + r15, g*8)];
      acc[nb] = MFMA16(vf0, pf0, acc[nb]);
    }
#pragma unroll
    for (int nb = 0; nb < 4; ++nb){
      bf16x8 vf1 = *(const bf16x8*)&VTs[SW(nb*16 + r15, 32 + g*8)];
      acc[nb] = MFMA16(vf1, pf1, acc[nb]);
    }
    __builtin_amdgcn_s_setprio(0);
    __builtin_amdgcn_s_barrier();       // all reads of tile j done -> next FSTG may overwrite
  }
#undef FSTG

  // epilogue: one cross-g reduce for l, then normalize + store
  pl += __shfl_xor(pl, 16);
  pl += __shfl_xor(pl, 32);
  float inv = 1.0f / pl;
  size_t orow = (size_t)(wq + r15) * 1024;
#pragma unroll
  for (int nb = 0; nb < 4; ++nb){
    u16x4 o;
    o.x = f2bf(acc[nb][0] * inv);
    o.y = f2bf(acc[nb][1] * inv);
    o.z = f2bf(acc[nb][2] * inv);
    o.w = f2bf(acc[nb][3] * inv);
    *(u16x4*)&O[orow + nb*16 + g*4] = o;
  }
}

extern "C" void kernel_launch(void* const* d_in, const int* in_sizes, int n_in,
                              void* d_out, int out_size, void* d_ws, size_t ws_size,
                              hipStream_t stream){
  const float* x    = (const float*)d_in[0];
  const float* xa   = (const float*)d_in[1];
  const float* lnw  = (const float*)d_in[2];
  const float* lnb  = (const float*)d_in[3];
  const float* Wq   = (const float*)d_in[4];
  const float* Wkv  = (const float*)d_in[5];
  const float* Wout = (const float*)d_in[6];
  float* out = (float*)d_out;
  char* ws = (char*)d_ws;
  const size_t MB = 1ull << 20;
  u16* xn  = (u16*)(ws);
  u16* xan = (u16*)(ws + 8*MB);
  u16* q   = (u16*)(ws + 16*MB);
  u16* vT  = (u16*)(ws + 24*MB);
  u16* ka  = (u16*)(ws + 32*MB);
  u16* vaT = (u16*)(ws + 40*MB);
  u16* xu  = (u16*)(ws + 48*MB);   // xu..xau contiguous -> M=8192 out-GEMM
  u16* xau = (u16*)(ws + 56*MB);
  u16* WqT = (u16*)(ws + 64*MB);
  u16* WkT = (u16*)(ws + 66*MB);
  u16* WvT = (u16*)(ws + 68*MB);
  u16* WoT = (u16*)(ws + 70*MB);
  dim3 blk(256);
  // fused prep: 8192 LN rows + 1024 transpose tiles in one launch
  prep<<<dim3(9216), blk, 0, stream>>>(x, xa, lnw, lnb, Wq, Wkv, Wout,
                                       xn, xan, WqT, WkT, WvT, WoT);
  // proj: quads 0:q, 1:vT(tr), 2:ka, 3:vaT(tr). 1-D 256 blocks, XCD-grouped.
  gemm256<256, 4, 0xA, u16><<<dim3(256), dim3(512), 0, stream>>>(
      xn, xn, xan, xan, WqT, WvT, WkT, WvT, q, vT, ka, vaT);
  flash<<<dim3(2048), blk, 0, stream>>>(q, vT, ka, vaT, xu, xau);
  // out: single M=8192 GEMM (xu||xau) @ WoT -> (out0||out1) f32. 256 blocks.
  gemm256<128, 1, 0, float><<<dim3(256), dim3(512), 0, stream>>>(
      xu, xu, xu, xu, WoT, WoT, WoT, WoT, out, out, out, out);
}